// Round 1
// baseline (8371.198 us; speedup 1.0000x reference)
//
#include <hip/hip_runtime.h>
#include <hip/hip_bf16.h>

#define T_STEPS 128
#define BATCH   32
#define IN_DIM  512
#define H_DIM   1024
#define OUT_DIM 8192
#define KH      3072   // (K-1)*H

typedef __attribute__((ext_vector_type(8))) short short8;
typedef __attribute__((ext_vector_type(4))) float f32x4;

__device__ __forceinline__ unsigned short bf16_rne(float f) {
  unsigned u = __float_as_uint(f);
  unsigned r = (u + 0x7FFFu + ((u >> 16) & 1u)) >> 16;
  return (unsigned short)r;
}

__device__ __forceinline__ void gload_lds16(const void* g, void* l) {
  __builtin_amdgcn_global_load_lds(
      (const __attribute__((address_space(1))) void*)g,
      (__attribute__((address_space(3))) void*)l, 16, 0, 0);
}

// ---------------- Wmo f32 -> bf16 ----------------
__global__ __launch_bounds__(256) void convert_kernel(
    const float* __restrict__ src, unsigned short* __restrict__ dst, int n4) {
  int i = blockIdx.x * blockDim.x + threadIdx.x;
  const int stride = gridDim.x * blockDim.x;
  for (; i < n4; i += stride) {
    float4 v = ((const float4*)src)[i];
    ushort4 o;
    o.x = bf16_rne(v.x); o.y = bf16_rne(v.y);
    o.z = bf16_rne(v.z); o.w = bf16_rne(v.w);
    ((ushort4*)dst)[i] = o;
  }
}

// ---------------- pre[t][j][b] = X@Wxh^T + bias (fp32, transposed store) ----
__global__ __launch_bounds__(256) void pre_kernel(
    const float* __restrict__ X, const float* __restrict__ Wxh,
    const float* __restrict__ bias, float* __restrict__ preT) {
  __shared__ float xs[32][260];   // pad 260: float4-aligned, 2-way-max banks
  const int tid = threadIdx.x;
  const int t  = blockIdx.x >> 4;
  const int jb = blockIdx.x & 15;
  const int b  = tid & 31;
  const int jg = tid >> 5;        // 0..7
  float acc[8];
  #pragma unroll
  for (int i = 0; i < 8; ++i) acc[i] = 0.f;

  for (int kc = 0; kc < 2; ++kc) {
    __syncthreads();
    #pragma unroll
    for (int v = tid; v < 2048; v += 256) {   // stage X[t][*][kc*256..+256)
      int br = v >> 6, i4 = v & 63;
      float4 x4 = *(const float4*)(X + (size_t)t*(BATCH*IN_DIM) + (size_t)br*IN_DIM + kc*256 + i4*4);
      *(float4*)&xs[br][i4*4] = x4;
    }
    __syncthreads();
    for (int i = 0; i < 256; i += 4) {
      const int k = kc*256 + i;
      float4 xv = *(const float4*)&xs[b][i];
      #pragma unroll
      for (int jj = 0; jj < 8; ++jj) {
        const int j = jb*64 + jg + jj*8;
        float4 w4 = *(const float4*)(Wxh + (size_t)j*IN_DIM + k);
        acc[jj] += xv.x*w4.x + xv.y*w4.y + xv.z*w4.z + xv.w*w4.w;
      }
    }
  }
  #pragma unroll
  for (int jj = 0; jj < 8; ++jj) {
    const int j = jb*64 + jg + jj*8;
    preT[(size_t)t*(H_DIM*BATCH) + (size_t)j*BATCH + b] = acc[jj] + bias[j];
  }
}

// ---------------- one recurrence step (fp32) -------------------------------
// grid 256 = 32 jb x 8 kb ; 512 threads = 8 bg(4b) x 32 jg x 2 ks(192k)
// hbufT[s][j][b], s = 3 + t (s=0..2 zeros). partials[16][1024][32].
// Last WG per jb (atomic count) reduces 16 partials + pre, selu, writes
// hbufT and the bf16 gathered-A rows.
__global__ __launch_bounds__(512) void step_kernel(
    const float* __restrict__ Whh, const float* __restrict__ preT,
    float* __restrict__ hbufT, float* __restrict__ partials,
    unsigned short* __restrict__ A16, int* __restrict__ done, const int t) {
  __shared__ int lflag;
  __shared__ unsigned short lds_h[32][34];
  const int tid = threadIdx.x;
  const int jb = blockIdx.x & 31;
  const int kb = blockIdx.x >> 5;
  const int bg = tid & 7;
  const int jg = (tid >> 3) & 31;
  const int ks = tid >> 8;
  const int j  = jb*32 + jg;
  const int k0 = kb*384 + ks*192;

  float4 acc; acc.x = acc.y = acc.z = acc.w = 0.f;
  const float* wrow = Whh + (size_t)j*KH;
  int kg = k0;
  const int kend = k0 + 192;
  while (kg < kend) {
    const int dk = kg >> 10;                   // 0 -> h_{t-1} (newest first)
    const int s  = t + 2 - dk;                 // hbufT slot of h_{t-1-dk}
    const int kstop = min(kend, (dk + 1) << 10);
    const float4* hp = (const float4*)(hbufT + ((size_t)s*H_DIM + (kg & 1023))*BATCH) + bg;
    const float* wp = wrow + kg;
    const int n = kstop - kg;
    #pragma unroll 4
    for (int i = 0; i < n; i += 4) {
      float4 w4 = *(const float4*)(wp + i);
      float4 h0 = hp[(i+0)*8];
      float4 h1 = hp[(i+1)*8];
      float4 h2 = hp[(i+2)*8];
      float4 h3 = hp[(i+3)*8];
      acc.x += h0.x*w4.x + h1.x*w4.y + h2.x*w4.z + h3.x*w4.w;
      acc.y += h0.y*w4.x + h1.y*w4.y + h2.y*w4.z + h3.y*w4.w;
      acc.z += h0.z*w4.x + h1.z*w4.y + h2.z*w4.z + h3.z*w4.w;
      acc.w += h0.w*w4.x + h1.w*w4.y + h2.w*w4.z + h3.w*w4.w;
    }
    kg = kstop;
  }
  const int pk = kb*2 + ks;
  *(float4*)(partials + ((size_t)pk*H_DIM + j)*BATCH + bg*4) = acc;
  __threadfence();               // release partials (cross-XCD: wb L2)
  __syncthreads();
  if (tid == 0) lflag = (atomicAdd(&done[jb], 1) == 7);
  __syncthreads();
  if (!lflag) return;

  // ---- finalizer for this jb ----
  __threadfence();               // acquire (invalidate stale L2 lines)
  #pragma unroll
  for (int pass = 0; pass < 2; ++pass) {
    const int oi = pass*512 + tid;
    const int jj = oi >> 5, b = oi & 31;
    const int jg2 = jb*32 + jj;
    float u = preT[((size_t)t*H_DIM + jg2)*BATCH + b];
    #pragma unroll
    for (int p = 0; p < 16; ++p)
      u += partials[((size_t)p*H_DIM + jg2)*BATCH + b];
    const float h = u > 0.f ? 1.0507009873554805f*u
                            : (1.0507009873554805f*1.6732632423543772f)*expm1f(u);
    hbufT[((size_t)(3+t)*H_DIM + jg2)*BATCH + b] = h;
    lds_h[jj][b] = bf16_rne(h);
  }
  if (tid == 0) done[jb] = 0;    // ready for next step's launch
  __syncthreads();
  // scatter h_t into gathered-A rows: A16[(t+dk)*32+b][dk*1024 + j]
  const int jv = tid & 15, b2 = tid >> 4;
  #pragma unroll
  for (int dkk = 0; dkk < 4; ++dkk) {
    const int tt = t + dkk;
    if (tt >= T_STEPS) break;
    ushort2 v;
    v.x = lds_h[jv*2][b2];
    v.y = lds_h[jv*2+1][b2];
    *(ushort2*)(A16 + ((size_t)(tt*BATCH + b2))*4096 + dkk*1024 + jb*32 + jv*2) = v;
  }
}

// ---------------- out = A16 @ Wmo16^T  (bf16 MFMA, 128x128 tile) -----------
__global__ __launch_bounds__(256) void gemm_kernel(
    const unsigned short* __restrict__ A, const unsigned short* __restrict__ Bm,
    float* __restrict__ C) {
  __shared__ __align__(16) unsigned short lA[4096];  // [128 rows][32 k]
  __shared__ __align__(16) unsigned short lB[4096];
  const int tid = threadIdx.x;
  const int wg = blockIdx.x;
  const int swz = (wg & 7)*256 + (wg >> 3);          // XCD swizzle (2048%8==0)
  const int mb = swz >> 6;                           // 32 m-tiles
  const int nb = swz & 63;                           // 64 n-tiles
  const int lane = tid & 63;
  const int wv = tid >> 6;
  const int wm = wv >> 1, wn = wv & 1;
  const int lrow = lane & 15, lhalf = lane >> 4;
  const int rowA = tid >> 2, qA = tid & 3;
  f32x4 acc[4][4] = {};

  for (int kt = 0; kt < 128; ++kt) {
    __syncthreads();
    #pragma unroll
    for (int it = 0; it < 2; ++it) {
      const int row = it*64 + rowA;
      gload_lds16(A  + (size_t)(mb*128 + row)*4096 + kt*32 + qA*8,
                  &lA[(tid & 192)*8 + it*2048]);
      gload_lds16(Bm + (size_t)(nb*128 + row)*4096 + kt*32 + qA*8,
                  &lB[(tid & 192)*8 + it*2048]);
    }
    __syncthreads();   // barrier drains vmcnt -> LDS valid
    short8 af[4], bf[4];
    #pragma unroll
    for (int mi = 0; mi < 4; ++mi)
      af[mi] = *(const short8*)&lA[(wm*64 + mi*16 + lrow)*32 + lhalf*8];
    #pragma unroll
    for (int ni = 0; ni < 4; ++ni)
      bf[ni] = *(const short8*)&lB[(wn*64 + ni*16 + lrow)*32 + lhalf*8];
    #pragma unroll
    for (int mi = 0; mi < 4; ++mi)
      #pragma unroll
      for (int ni = 0; ni < 4; ++ni)
        acc[mi][ni] = __builtin_amdgcn_mfma_f32_16x16x32_bf16(af[mi], bf[ni], acc[mi][ni], 0, 0, 0);
  }
  const int orow0 = mb*128 + wm*64 + lhalf*4;
  const int ocol0 = nb*128 + wn*64 + lrow;
  #pragma unroll
  for (int mi = 0; mi < 4; ++mi)
    #pragma unroll
    for (int ni = 0; ni < 4; ++ni)
      #pragma unroll
      for (int q = 0; q < 4; ++q)
        C[(size_t)(orow0 + mi*16 + q)*OUT_DIM + ocol0 + ni*16] = acc[mi][ni][q];
}

extern "C" void kernel_launch(void* const* d_in, const int* in_sizes, int n_in,
                              void* d_out, int out_size, void* d_ws, size_t ws_size,
                              hipStream_t stream) {
  (void)in_sizes; (void)n_in; (void)out_size; (void)ws_size;
  const float* X   = (const float*)d_in[0];
  const float* Wxh = (const float*)d_in[1];
  const float* Wxb = (const float*)d_in[2];
  const float* Whh = (const float*)d_in[3];
  const float* Wmo = (const float*)d_in[4];
  float* out = (float*)d_out;
  char* ws = (char*)d_ws;

  const size_t OFF_PRET = 0;
  const size_t OFF_HBUF = OFF_PRET + (size_t)T_STEPS*H_DIM*BATCH*4;        // 16 MB
  const size_t OFF_PART = OFF_HBUF + (size_t)(T_STEPS+3)*H_DIM*BATCH*4;   // +17 MB
  const size_t OFF_DONE = OFF_PART + (size_t)16*H_DIM*BATCH*4;            // +2 MB
  const size_t OFF_A16  = OFF_DONE + 256;
  const size_t OFF_W16  = OFF_A16 + (size_t)4096*4096*2;                  // +33.5 MB

  float* preT      = (float*)(ws + OFF_PRET);
  float* hbufT     = (float*)(ws + OFF_HBUF);
  float* partials  = (float*)(ws + OFF_PART);
  int*   done      = (int*)(ws + OFF_DONE);
  unsigned short* A16   = (unsigned short*)(ws + OFF_A16);
  unsigned short* Wmo16 = (unsigned short*)(ws + OFF_W16);

  hipMemsetAsync(hbufT, 0, (size_t)3*H_DIM*BATCH*4, stream);   // zero history
  hipMemsetAsync(done, 0, 32*4, stream);                       // barrier ctrs
  hipMemsetAsync(A16, 0, (size_t)96*4096*2, stream);           // t<3 zero cols

  convert_kernel<<<2048, 256, 0, stream>>>(Wmo, Wmo16, (int)((size_t)OUT_DIM*4096/4));
  pre_kernel<<<2048, 256, 0, stream>>>(X, Wxh, Wxb, preT);
  for (int t = 0; t < T_STEPS; ++t)
    step_kernel<<<256, 512, 0, stream>>>(Whh, preT, hbufT, partials, A16, done, t);
  gemm_kernel<<<2048, 256, 0, stream>>>(A16, Wmo16, out);
}

// Round 2
// 5747.255 us; speedup vs baseline: 1.4566x; 1.4566x over previous
//
#include <hip/hip_runtime.h>
#include <hip/hip_bf16.h>

#define T_STEPS 128
#define BATCH   32
#define IN_DIM  512
#define H_DIM   1024
#define OUT_DIM 8192
#define KH      3072   // (K-1)*H
#define NWG     256

typedef __attribute__((ext_vector_type(8))) short short8;
typedef __attribute__((ext_vector_type(4))) float f32x4;

__device__ __forceinline__ unsigned short bf16_rne(float f) {
  unsigned u = __float_as_uint(f);
  unsigned r = (u + 0x7FFFu + ((u >> 16) & 1u)) >> 16;
  return (unsigned short)r;
}

__device__ __forceinline__ void gload_lds16(const void* g, void* l) {
  __builtin_amdgcn_global_load_lds(
      (const __attribute__((address_space(1))) void*)g,
      (__attribute__((address_space(3))) void*)l, 16, 0, 0);
}

// ---------------- Wmo f32 -> bf16 ----------------
__global__ __launch_bounds__(256) void convert_kernel(
    const float* __restrict__ src, unsigned short* __restrict__ dst, int n4) {
  int i = blockIdx.x * blockDim.x + threadIdx.x;
  const int stride = gridDim.x * blockDim.x;
  for (; i < n4; i += stride) {
    float4 v = ((const float4*)src)[i];
    ushort4 o;
    o.x = bf16_rne(v.x); o.y = bf16_rne(v.y);
    o.z = bf16_rne(v.z); o.w = bf16_rne(v.w);
    ((ushort4*)dst)[i] = o;
  }
}

// ---------------- pre[t][j][b] = X@Wxh^T + bias (fp32, transposed store) ----
__global__ __launch_bounds__(256) void pre_kernel(
    const float* __restrict__ X, const float* __restrict__ Wxh,
    const float* __restrict__ bias, float* __restrict__ preT) {
  __shared__ float xs[32][260];
  const int tid = threadIdx.x;
  const int t  = blockIdx.x >> 4;
  const int jb = blockIdx.x & 15;
  const int b  = tid & 31;
  const int jg = tid >> 5;        // 0..7
  float acc[8];
  #pragma unroll
  for (int i = 0; i < 8; ++i) acc[i] = 0.f;

  for (int kc = 0; kc < 2; ++kc) {
    __syncthreads();
    #pragma unroll
    for (int v = tid; v < 2048; v += 256) {
      int br = v >> 6, i4 = v & 63;
      float4 x4 = *(const float4*)(X + (size_t)t*(BATCH*IN_DIM) + (size_t)br*IN_DIM + kc*256 + i4*4);
      *(float4*)&xs[br][i4*4] = x4;
    }
    __syncthreads();
    for (int i = 0; i < 256; i += 4) {
      const int k = kc*256 + i;
      float4 xv = *(const float4*)&xs[b][i];
      #pragma unroll
      for (int jj = 0; jj < 8; ++jj) {
        const int j = jb*64 + jg + jj*8;
        float4 w4 = *(const float4*)(Wxh + (size_t)j*IN_DIM + k);
        acc[jj] += xv.x*w4.x + xv.y*w4.y + xv.z*w4.z + xv.w*w4.w;
      }
    }
  }
  #pragma unroll
  for (int jj = 0; jj < 8; ++jj) {
    const int j = jb*64 + jg + jj*8;
    preT[(size_t)t*(H_DIM*BATCH) + (size_t)j*BATCH + b] = acc[jj] + bias[j];
  }
}

// ---------------- persistent recurrence kernel -----------------------------
// 256 WGs x 512 thr. WG owns j = wg*4..+4; Whh rows staged in LDS once.
// Per step: all-k dot for own 4 j rows (thread = b x ks16), LDS reduce,
// selu, write h (fp32) + A16 (bf16), grid barrier.
__global__ __launch_bounds__(512) void recur_kernel(
    const float* __restrict__ Whh, const float* __restrict__ preT,
    float* __restrict__ hbufT, unsigned short* __restrict__ A16,
    int* __restrict__ bar) {   // bar[0]=cnt, bar[1]=gen
  __shared__ float w_lds[4][3072];       // 48 KB
  __shared__ float red[16][32][4];       // 8 KB
  const int tid = threadIdx.x;
  const int wg  = blockIdx.x;
  const int j0  = wg * 4;

  // stage Whh rows (once; survives all steps, immune to L2 invalidation)
  for (int v = tid; v < 3072; v += 512) {       // 3072 float4 total
    const int jj = v >> 10, kk = (v & 1023) * 4 * 3; // careful: map below
    (void)jj; (void)kk;
  }
  // simpler explicit staging: 12288 floats = 3072 float4
  for (int v = tid; v < 3072; v += 512) {
    const int jj = v / 768;
    const int kk = (v - jj*768) * 4;
    *(float4*)&w_lds[jj][kk] = *(const float4*)(Whh + (size_t)(j0 + jj)*KH + kk);
  }
  __syncthreads();

  const int b  = tid & 31;
  const int ks = tid >> 5;     // 0..15, k-slice of 192

  for (int t = 0; t < T_STEPS; ++t) {
    float a0 = 0.f, a1 = 0.f, a2 = 0.f, a3 = 0.f;
    int k = ks * 192;
    const int kend = k + 192;
    while (k < kend) {
      const int dk   = k >> 10;
      const int kst  = min(kend, (dk + 1) << 10);
      const float* hb = hbufT + ((size_t)(t + 2 - dk)*H_DIM + (k & 1023))*BATCH + b;
      const int n = kst - k;
      #pragma unroll 4
      for (int i = 0; i < n; i += 4) {
        const float h0 = hb[(i+0)*32];
        const float h1 = hb[(i+1)*32];
        const float h2 = hb[(i+2)*32];
        const float h3 = hb[(i+3)*32];
        const float4 w0 = *(const float4*)&w_lds[0][k + i];
        const float4 w1 = *(const float4*)&w_lds[1][k + i];
        const float4 w2 = *(const float4*)&w_lds[2][k + i];
        const float4 w3 = *(const float4*)&w_lds[3][k + i];
        a0 += h0*w0.x + h1*w0.y + h2*w0.z + h3*w0.w;
        a1 += h0*w1.x + h1*w1.y + h2*w1.z + h3*w1.w;
        a2 += h0*w2.x + h1*w2.y + h2*w2.z + h3*w2.w;
        a3 += h0*w3.x + h1*w3.y + h2*w3.z + h3*w3.w;
      }
      k = kst;
    }
    red[ks][b][0] = a0; red[ks][b][1] = a1;
    red[ks][b][2] = a2; red[ks][b][3] = a3;
    __syncthreads();
    if (tid < 128) {
      const int jj = tid >> 5, bb = tid & 31;
      float u = preT[((size_t)t*H_DIM + j0 + jj)*BATCH + bb];
      #pragma unroll
      for (int p = 0; p < 16; ++p) u += red[p][bb][jj];
      const float h = u > 0.f ? 1.0507009873554805f*u
                              : (1.0507009873554805f*1.6732632423543772f)*expm1f(u);
      hbufT[((size_t)(3 + t)*H_DIM + j0 + jj)*BATCH + bb] = h;
      const unsigned short h16 = bf16_rne(h);
      #pragma unroll
      for (int dk2 = 0; dk2 < 4; ++dk2) {
        const int tt = t + dk2;
        if (tt < T_STEPS)
          A16[((size_t)(tt*BATCH + bb))*4096 + dk2*H_DIM + j0 + jj] = h16;
      }
    }
    // ---- grid barrier (sense via generation counter) ----
    __syncthreads();
    if (tid == 0) {
      __threadfence();   // release: flush this XCD's L2 (h writes visible)
      const int g = __hip_atomic_load(&bar[1], __ATOMIC_RELAXED, __HIP_MEMORY_SCOPE_AGENT);
      if (atomicAdd(&bar[0], 1) == NWG - 1) {
        __hip_atomic_store(&bar[0], 0, __ATOMIC_RELAXED, __HIP_MEMORY_SCOPE_AGENT);
        __threadfence();
        __hip_atomic_fetch_add(&bar[1], 1, __ATOMIC_RELAXED, __HIP_MEMORY_SCOPE_AGENT);
      } else {
        while (__hip_atomic_load(&bar[1], __ATOMIC_RELAXED, __HIP_MEMORY_SCOPE_AGENT) == g)
          __builtin_amdgcn_s_sleep(2);
      }
      __threadfence();   // acquire: invalidate stale L2 lines
    }
    __syncthreads();
  }
}

// ---------------- out = A16 @ Wmo16^T  (bf16 MFMA, 128x128 tile) -----------
__global__ __launch_bounds__(256) void gemm_kernel(
    const unsigned short* __restrict__ A, const unsigned short* __restrict__ Bm,
    float* __restrict__ C) {
  __shared__ __align__(16) unsigned short lA[4096];  // [128 rows][32 k]
  __shared__ __align__(16) unsigned short lB[4096];
  const int tid = threadIdx.x;
  const int wg = blockIdx.x;
  // 2D-chunked XCD swizzle: XCD x owns mb [ (x>>2)*16, +16 ), nb [ (x&3)*16, +16 )
  const int x = wg & 7;
  const int c = wg >> 3;                 // 0..255 within chunk
  const int mb = (x >> 2)*16 + (c & 15);
  const int nb = (x & 3)*16 + (c >> 4);
  const int lane = tid & 63;
  const int wv = tid >> 6;
  const int wm = wv >> 1, wn = wv & 1;
  const int lrow = lane & 15, lhalf = lane >> 4;
  const int rowA = tid >> 2, qA = tid & 3;
  f32x4 acc[4][4] = {};

  for (int kt = 0; kt < 128; ++kt) {
    __syncthreads();
    #pragma unroll
    for (int it = 0; it < 2; ++it) {
      const int row = it*64 + rowA;
      gload_lds16(A  + (size_t)(mb*128 + row)*4096 + kt*32 + qA*8,
                  &lA[(tid & 192)*8 + it*2048]);
      gload_lds16(Bm + (size_t)(nb*128 + row)*4096 + kt*32 + qA*8,
                  &lB[(tid & 192)*8 + it*2048]);
    }
    __syncthreads();   // barrier drains vmcnt -> LDS valid
    short8 af[4], bf[4];
    #pragma unroll
    for (int mi = 0; mi < 4; ++mi)
      af[mi] = *(const short8*)&lA[(wm*64 + mi*16 + lrow)*32 + lhalf*8];
    #pragma unroll
    for (int ni = 0; ni < 4; ++ni)
      bf[ni] = *(const short8*)&lB[(wn*64 + ni*16 + lrow)*32 + lhalf*8];
    #pragma unroll
    for (int mi = 0; mi < 4; ++mi)
      #pragma unroll
      for (int ni = 0; ni < 4; ++ni)
        acc[mi][ni] = __builtin_amdgcn_mfma_f32_16x16x32_bf16(af[mi], bf[ni], acc[mi][ni], 0, 0, 0);
  }
  const int orow0 = mb*128 + wm*64 + lhalf*4;
  const int ocol0 = nb*128 + wn*64 + lrow;
  #pragma unroll
  for (int mi = 0; mi < 4; ++mi)
    #pragma unroll
    for (int ni = 0; ni < 4; ++ni)
      #pragma unroll
      for (int q = 0; q < 4; ++q)
        __builtin_nontemporal_store(acc[mi][ni][q],
            &C[(size_t)(orow0 + mi*16 + q)*OUT_DIM + ocol0 + ni*16]);
}

extern "C" void kernel_launch(void* const* d_in, const int* in_sizes, int n_in,
                              void* d_out, int out_size, void* d_ws, size_t ws_size,
                              hipStream_t stream) {
  (void)in_sizes; (void)n_in; (void)out_size; (void)ws_size;
  const float* X   = (const float*)d_in[0];
  const float* Wxh = (const float*)d_in[1];
  const float* Wxb = (const float*)d_in[2];
  const float* Whh = (const float*)d_in[3];
  const float* Wmo = (const float*)d_in[4];
  float* out = (float*)d_out;
  char* ws = (char*)d_ws;

  const size_t OFF_PRET = 0;
  const size_t OFF_HBUF = OFF_PRET + (size_t)T_STEPS*H_DIM*BATCH*4;        // 16 MB
  const size_t OFF_BAR  = OFF_HBUF + (size_t)(T_STEPS+3)*H_DIM*BATCH*4;   // +17 MB
  const size_t OFF_A16  = OFF_BAR + 256;
  const size_t OFF_W16  = OFF_A16 + (size_t)4096*4096*2;                  // +33.5 MB

  float* preT      = (float*)(ws + OFF_PRET);
  float* hbufT     = (float*)(ws + OFF_HBUF);
  int*   bar       = (int*)(ws + OFF_BAR);
  unsigned short* A16   = (unsigned short*)(ws + OFF_A16);
  unsigned short* Wmo16 = (unsigned short*)(ws + OFF_W16);

  hipMemsetAsync(hbufT, 0, (size_t)3*H_DIM*BATCH*4, stream);   // zero history
  hipMemsetAsync(bar, 0, 256, stream);                         // barrier state
  hipMemsetAsync(A16, 0, (size_t)96*4096*2, stream);           // t<3 zero cols

  convert_kernel<<<2048, 256, 0, stream>>>(Wmo, Wmo16, (int)((size_t)OUT_DIM*4096/4));
  pre_kernel<<<2048, 256, 0, stream>>>(X, Wxh, Wxb, preT);
  recur_kernel<<<NWG, 512, 0, stream>>>(Whh, preT, hbufT, A16, bar);
  gemm_kernel<<<2048, 256, 0, stream>>>(A16, Wmo16, out);
}

// Round 4
// 3625.341 us; speedup vs baseline: 2.3091x; 1.5853x over previous
//
#include <hip/hip_runtime.h>
#include <hip/hip_bf16.h>

#define T_STEPS 128
#define BATCH   32
#define IN_DIM  512
#define H_DIM   1024
#define OUT_DIM 8192
#define KH      3072   // (K-1)*H
#define NWG     128
#define SLOT_E  32768  // elements per h slot (1024 k * 32 b)
#define NSLOT   131    // h_t stored at slot 127-t; slots 128..130 = zeros

typedef __attribute__((ext_vector_type(8))) short short8;
typedef __attribute__((ext_vector_type(4))) float f32x4;

__device__ __forceinline__ unsigned short bf16_rne(float f) {
  unsigned u = __float_as_uint(f);
  unsigned r = (u + 0x7FFFu + ((u >> 16) & 1u)) >> 16;
  return (unsigned short)r;
}

__device__ __forceinline__ void gload_lds16(const void* g, void* l) {
  __builtin_amdgcn_global_load_lds(
      (const __attribute__((address_space(1))) void*)g,
      (__attribute__((address_space(3))) void*)l, 16, 0, 0);
}

// ---------------- Wmo f32 -> bf16 ----------------
__global__ __launch_bounds__(256) void convert_kernel(
    const float* __restrict__ src, unsigned short* __restrict__ dst, int n4) {
  int i = blockIdx.x * blockDim.x + threadIdx.x;
  const int stride = gridDim.x * blockDim.x;
  for (; i < n4; i += stride) {
    float4 v = ((const float4*)src)[i];
    ushort4 o;
    o.x = bf16_rne(v.x); o.y = bf16_rne(v.y);
    o.z = bf16_rne(v.z); o.w = bf16_rne(v.w);
    ((ushort4*)dst)[i] = o;
  }
}

// ---------------- pre[t][j][b] = X@Wxh^T + bias (fp32) ---------------------
__global__ __launch_bounds__(256) void pre_kernel(
    const float* __restrict__ X, const float* __restrict__ Wxh,
    const float* __restrict__ bias, float* __restrict__ preT) {
  __shared__ float xs[32][260];
  const int tid = threadIdx.x;
  const int t  = blockIdx.x >> 4;
  const int jb = blockIdx.x & 15;
  const int b  = tid & 31;
  const int jg = tid >> 5;        // 0..7
  float acc[8];
  #pragma unroll
  for (int i = 0; i < 8; ++i) acc[i] = 0.f;

  for (int kc = 0; kc < 2; ++kc) {
    __syncthreads();
    #pragma unroll
    for (int v = tid; v < 2048; v += 256) {
      int br = v >> 6, i4 = v & 63;
      float4 x4 = *(const float4*)(X + (size_t)t*(BATCH*IN_DIM) + (size_t)br*IN_DIM + kc*256 + i4*4);
      *(float4*)&xs[br][i4*4] = x4;
    }
    __syncthreads();
    for (int i = 0; i < 256; i += 4) {
      const int k = kc*256 + i;
      float4 xv = *(const float4*)&xs[b][i];
      #pragma unroll
      for (int jj = 0; jj < 8; ++jj) {
        const int j = jb*64 + jg + jj*8;
        float4 w4 = *(const float4*)(Wxh + (size_t)j*IN_DIM + k);
        acc[jj] += xv.x*w4.x + xv.y*w4.y + xv.z*w4.z + xv.w*w4.w;
      }
    }
  }
  #pragma unroll
  for (int jj = 0; jj < 8; ++jj) {
    const int j = jb*64 + jg + jj*8;
    preT[(size_t)t*(H_DIM*BATCH) + (size_t)j*BATCH + b] = acc[jj] + bias[j];
  }
}

// ---------------- persistent MFMA recurrence -------------------------------
// 128 WGs x 512 thr; WG owns j rows j0..j0+7. A-tile rows 0-7 = bf16-hi(Whh),
// rows 8-15 = bf16-lo residual -> one mfma computes both. h stored as hi/lo
// bf16 buffers in B-fragment order, slot index 127-t so h_cat is contiguous.
__global__ __launch_bounds__(512) void recur_kernel(
    const float* __restrict__ Whh, const float* __restrict__ preT,
    unsigned short* __restrict__ hHi, unsigned short* __restrict__ hLo,
    unsigned short* __restrict__ A16, int* __restrict__ bar) {
  __shared__ __align__(16) unsigned short w_lds[96*64*8];  // 96 KB A-fragments
  __shared__ float red[8][16][33];                         // padded: 2-way banks
  const int tid  = threadIdx.x;
  const int wg   = blockIdx.x;
  const int j0   = wg * 8;
  const int lane = tid & 63;
  const int wv   = tid >> 6;       // wave 0..7

  // ---- stage Whh as hi/lo mfma A-fragments (once) ----
  for (int s = tid; s < 6144; s += 512) {
    const int ks = s >> 6, l = s & 63;
    const int r = l & 15;                 // A-row: 0-7 hi, 8-15 lo
    const int j = j0 + (r & 7);
    const int part = r >> 3;
    const int kb = ks*32 + (l >> 4)*8;
    const float* wp = Whh + (size_t)j*KH + kb;
    unsigned short tmp[8];
    #pragma unroll
    for (int i = 0; i < 8; ++i) {
      const float f = wp[i];
      unsigned short v = bf16_rne(f);
      if (part) v = bf16_rne(f - __uint_as_float((unsigned)v << 16));
      tmp[i] = v;
    }
    *(short8*)&w_lds[s*8] = *(short8*)tmp;
  }
  __syncthreads();

  const short8* wf  = (const short8*)w_lds;
  const short8* hi8 = (const short8*)hHi;
  const short8* lo8 = (const short8*)hLo;

  for (int t = 0; t < T_STEPS; ++t) {
    const size_t sb = (size_t)(128 - t) * 4096;   // slot base, 16B units
    f32x4 a0h = {}, a0l = {}, a1h = {}, a1l = {}; // [btile][h-part]
    const int ks0 = wv * 12;
    #pragma unroll 4
    for (int kk = 0; kk < 12; ++kk) {
      const int ks = ks0 + kk;
      const short8 af = wf[ks*64 + lane];
      const size_t bidx = sb + (size_t)(ks*4 + (lane >> 4))*32 + (lane & 15);
      const short8 b0h = hi8[bidx];
      const short8 b1h = hi8[bidx + 16];
      const short8 b0l = lo8[bidx];
      const short8 b1l = lo8[bidx + 16];
      a0h = __builtin_amdgcn_mfma_f32_16x16x32_bf16(af, b0h, a0h, 0, 0, 0);
      a1h = __builtin_amdgcn_mfma_f32_16x16x32_bf16(af, b1h, a1h, 0, 0, 0);
      a0l = __builtin_amdgcn_mfma_f32_16x16x32_bf16(af, b0l, a0l, 0, 0, 0);
      a1l = __builtin_amdgcn_mfma_f32_16x16x32_bf16(af, b1l, a1l, 0, 0, 0);
    }
    const f32x4 s0 = a0h + a0l;   // sum h-parts in-lane
    const f32x4 s1 = a1h + a1l;
    const int rr = (lane >> 4) * 4, cc = lane & 15;
    #pragma unroll
    for (int q = 0; q < 4; ++q) {
      red[wv][rr + q][cc]      = s0[q];
      red[wv][rr + q][16 + cc] = s1[q];
    }
    __syncthreads();
    if (tid < 256) {
      const int jj = tid >> 5, b = tid & 31;
      float u = preT[(size_t)t*(H_DIM*BATCH) + (size_t)(j0 + jj)*BATCH + b];
      #pragma unroll
      for (int w = 0; w < 8; ++w)
        u += red[w][jj][b] + red[w][jj + 8][b];   // + wlo rows
      const float h = u > 0.f ? 1.0507009873554805f*u
                              : (1.0507009873554805f*1.6732632423543772f)*expm1f(u);
      const unsigned short hh = bf16_rne(h);
      const unsigned short hl = bf16_rne(h - __uint_as_float((unsigned)hh << 16));
      const int j = j0 + jj;
      const size_t hidx = (size_t)(127 - t)*SLOT_E + (size_t)(j >> 3)*256 + (size_t)b*8 + (j & 7);
      hHi[hidx] = hh;
      hLo[hidx] = hl;
      #pragma unroll
      for (int dk = 0; dk < 4; ++dk) {
        const int tt = t + dk;
        if (tt < T_STEPS)
          A16[((size_t)(tt*BATCH + b))*4096 + dk*H_DIM + j] = hh;
      }
    }
    __syncthreads();
    if (t == T_STEPS - 1) break;
    if (tid == 0) {
      __threadfence();   // release: flush dirty L2 (h writes) to L3
      const int g = __hip_atomic_load(&bar[1], __ATOMIC_RELAXED, __HIP_MEMORY_SCOPE_AGENT);
      if (__hip_atomic_fetch_add(&bar[0], 1, __ATOMIC_RELAXED, __HIP_MEMORY_SCOPE_AGENT) == NWG - 1) {
        __hip_atomic_store(&bar[0], 0, __ATOMIC_RELAXED, __HIP_MEMORY_SCOPE_AGENT);
        __hip_atomic_fetch_add(&bar[1], 1, __ATOMIC_RELEASE, __HIP_MEMORY_SCOPE_AGENT);
      } else {
        while (__hip_atomic_load(&bar[1], __ATOMIC_RELAXED, __HIP_MEMORY_SCOPE_AGENT) == g)
          __builtin_amdgcn_s_sleep(2);
      }
      __threadfence();   // acquire: invalidate stale L1/L2 lines
    }
    __syncthreads();
  }
}

// ---------------- out = A16 @ Wmo16^T  (bf16 MFMA, 128x128 tile) -----------
__global__ __launch_bounds__(256) void gemm_kernel(
    const unsigned short* __restrict__ A, const unsigned short* __restrict__ Bm,
    float* __restrict__ C) {
  __shared__ __align__(16) unsigned short lA[4096];  // [128 rows][32 k]
  __shared__ __align__(16) unsigned short lB[4096];
  const int tid = threadIdx.x;
  const int wg = blockIdx.x;
  // 2D-chunked XCD swizzle: XCD x owns mb [(x>>2)*16,+16), nb [(x&3)*16,+16)
  const int x = wg & 7;
  const int c = wg >> 3;
  const int mb = (x >> 2)*16 + (c & 15);
  const int nb = (x & 3)*16 + (c >> 4);
  const int lane = tid & 63;
  const int wv = tid >> 6;
  const int wm = wv >> 1, wn = wv & 1;
  const int lrow = lane & 15, lhalf = lane >> 4;
  const int rowA = tid >> 2, qA = tid & 3;
  f32x4 acc[4][4] = {};

  for (int kt = 0; kt < 128; ++kt) {
    __syncthreads();
    #pragma unroll
    for (int it = 0; it < 2; ++it) {
      const int row = it*64 + rowA;
      gload_lds16(A  + (size_t)(mb*128 + row)*4096 + kt*32 + qA*8,
                  &lA[(tid & 192)*8 + it*2048]);
      gload_lds16(Bm + (size_t)(nb*128 + row)*4096 + kt*32 + qA*8,
                  &lB[(tid & 192)*8 + it*2048]);
    }
    __syncthreads();   // barrier drains vmcnt -> LDS valid
    short8 af[4], bf[4];
    #pragma unroll
    for (int mi = 0; mi < 4; ++mi)
      af[mi] = *(const short8*)&lA[(wm*64 + mi*16 + lrow)*32 + lhalf*8];
    #pragma unroll
    for (int ni = 0; ni < 4; ++ni)
      bf[ni] = *(const short8*)&lB[(wn*64 + ni*16 + lrow)*32 + lhalf*8];
    #pragma unroll
    for (int mi = 0; mi < 4; ++mi)
      #pragma unroll
      for (int ni = 0; ni < 4; ++ni)
        acc[mi][ni] = __builtin_amdgcn_mfma_f32_16x16x32_bf16(af[mi], bf[ni], acc[mi][ni], 0, 0, 0);
  }
  const int orow0 = mb*128 + wm*64 + lhalf*4;
  const int ocol0 = nb*128 + wn*64 + lrow;
  #pragma unroll
  for (int mi = 0; mi < 4; ++mi)
    #pragma unroll
    for (int ni = 0; ni < 4; ++ni)
      #pragma unroll
      for (int q = 0; q < 4; ++q)
        __builtin_nontemporal_store(acc[mi][ni][q],
            &C[(size_t)(orow0 + mi*16 + q)*OUT_DIM + ocol0 + ni*16]);
}

extern "C" void kernel_launch(void* const* d_in, const int* in_sizes, int n_in,
                              void* d_out, int out_size, void* d_ws, size_t ws_size,
                              hipStream_t stream) {
  (void)in_sizes; (void)n_in; (void)out_size; (void)ws_size;
  const float* X   = (const float*)d_in[0];
  const float* Wxh = (const float*)d_in[1];
  const float* Wxb = (const float*)d_in[2];
  const float* Whh = (const float*)d_in[3];
  const float* Wmo = (const float*)d_in[4];
  float* out = (float*)d_out;
  char* ws = (char*)d_ws;

  const size_t OFF_PRET = 0;                                               // 16.8 MB
  const size_t OFF_HHI  = OFF_PRET + (size_t)T_STEPS*H_DIM*BATCH*4;
  const size_t OFF_HLO  = OFF_HHI + (size_t)NSLOT*SLOT_E*2;                // +8.6 MB
  const size_t OFF_BAR  = OFF_HLO + (size_t)NSLOT*SLOT_E*2;                // +8.6 MB
  const size_t OFF_A16  = OFF_BAR + 256;
  const size_t OFF_W16  = OFF_A16 + (size_t)4096*4096*2;                   // +33.5 MB

  float* preT = (float*)(ws + OFF_PRET);
  unsigned short* hHi = (unsigned short*)(ws + OFF_HHI);
  unsigned short* hLo = (unsigned short*)(ws + OFF_HLO);
  int* bar = (int*)(ws + OFF_BAR);
  unsigned short* A16   = (unsigned short*)(ws + OFF_A16);
  unsigned short* Wmo16 = (unsigned short*)(ws + OFF_W16);

  // zero the three history slots (slots 128..130), barrier state, A16 t<3 cols
  hipMemsetAsync(hHi + (size_t)128*SLOT_E, 0, (size_t)3*SLOT_E*2, stream);
  hipMemsetAsync(hLo + (size_t)128*SLOT_E, 0, (size_t)3*SLOT_E*2, stream);
  hipMemsetAsync(bar, 0, 256, stream);
  hipMemsetAsync(A16, 0, (size_t)96*4096*2, stream);

  convert_kernel<<<2048, 256, 0, stream>>>(Wmo, Wmo16, (int)((size_t)OUT_DIM*4096/4));
  pre_kernel<<<2048, 256, 0, stream>>>(X, Wxh, Wxb, preT);
  recur_kernel<<<NWG, 512, 0, stream>>>(Whh, preT, hHi, hLo, A16, bar);
  gemm_kernel<<<2048, 256, 0, stream>>>(A16, Wmo16, out);
}

// Round 5
// 1341.294 us; speedup vs baseline: 6.2411x; 2.7029x over previous
//
#include <hip/hip_runtime.h>
#include <hip/hip_bf16.h>

#define T_STEPS 128
#define BATCH   32
#define IN_DIM  512
#define H_DIM   1024
#define OUT_DIM 8192
#define KH      3072   // (K-1)*H
#define NWG     128
#define SLOT_E  32768  // elements per h slot (1024 k * 32 b)
#define NSLOT   131    // h_t stored at slot 127-t; slots 128..130 = zeros

typedef __attribute__((ext_vector_type(8))) short short8;
typedef __attribute__((ext_vector_type(4))) float f32x4;

__device__ __forceinline__ unsigned short bf16_rne(float f) {
  unsigned u = __float_as_uint(f);
  unsigned r = (u + 0x7FFFu + ((u >> 16) & 1u)) >> 16;
  return (unsigned short)r;
}

__device__ __forceinline__ void gload_lds16(const void* g, void* l) {
  __builtin_amdgcn_global_load_lds(
      (const __attribute__((address_space(1))) void*)g,
      (__attribute__((address_space(3))) void*)l, 16, 0, 0);
}

// ---------------- Wmo f32 -> bf16 ----------------
__global__ __launch_bounds__(256) void convert_kernel(
    const float* __restrict__ src, unsigned short* __restrict__ dst, int n4) {
  int i = blockIdx.x * blockDim.x + threadIdx.x;
  const int stride = gridDim.x * blockDim.x;
  for (; i < n4; i += stride) {
    float4 v = ((const float4*)src)[i];
    ushort4 o;
    o.x = bf16_rne(v.x); o.y = bf16_rne(v.y);
    o.z = bf16_rne(v.z); o.w = bf16_rne(v.w);
    ((ushort4*)dst)[i] = o;
  }
}

// ---------------- pre[t][j][b] = X@Wxh^T + bias (fp32) ---------------------
__global__ __launch_bounds__(256) void pre_kernel(
    const float* __restrict__ X, const float* __restrict__ Wxh,
    const float* __restrict__ bias, float* __restrict__ preT) {
  __shared__ float xs[32][260];
  const int tid = threadIdx.x;
  const int t  = blockIdx.x >> 4;
  const int jb = blockIdx.x & 15;
  const int b  = tid & 31;
  const int jg = tid >> 5;        // 0..7
  float acc[8];
  #pragma unroll
  for (int i = 0; i < 8; ++i) acc[i] = 0.f;

  for (int kc = 0; kc < 2; ++kc) {
    __syncthreads();
    #pragma unroll
    for (int v = tid; v < 2048; v += 256) {
      int br = v >> 6, i4 = v & 63;
      float4 x4 = *(const float4*)(X + (size_t)t*(BATCH*IN_DIM) + (size_t)br*IN_DIM + kc*256 + i4*4);
      *(float4*)&xs[br][i4*4] = x4;
    }
    __syncthreads();
    for (int i = 0; i < 256; i += 4) {
      const int k = kc*256 + i;
      float4 xv = *(const float4*)&xs[b][i];
      #pragma unroll
      for (int jj = 0; jj < 8; ++jj) {
        const int j = jb*64 + jg + jj*8;
        float4 w4 = *(const float4*)(Wxh + (size_t)j*IN_DIM + k);
        acc[jj] += xv.x*w4.x + xv.y*w4.y + xv.z*w4.z + xv.w*w4.w;
      }
    }
  }
  #pragma unroll
  for (int jj = 0; jj < 8; ++jj) {
    const int j = jb*64 + jg + jj*8;
    preT[(size_t)t*(H_DIM*BATCH) + (size_t)j*BATCH + b] = acc[jj] + bias[j];
  }
}

// ---------------- persistent MFMA recurrence, flag-pipelined ---------------
// 128 WGs x 512 thr; WG owns 8 j rows. Whh hi/lo A-fragments resident in LDS.
// h exchanged via sc1 (agent-scope) stores + per-step ready counters; plain
// cached consumer loads (slot lines written once, read only post-flag).
// Per wave per step: phase A = 8 ks (dk1,dk2; no wait), poll ready[t-1],
// phase C = 4 ks (dk0).
__global__ __launch_bounds__(512) void recur_kernel(
    const float* __restrict__ Whh, const float* __restrict__ preT,
    unsigned short* __restrict__ hHi, unsigned short* __restrict__ hLo,
    unsigned short* __restrict__ A16, int* __restrict__ ready) {
  __shared__ __align__(16) unsigned short w_lds[96*64*8];  // 96 KB A-fragments
  __shared__ float red[8][16][33];
  __shared__ __align__(16) unsigned short hpk_hi[32][8];
  __shared__ __align__(16) unsigned short hpk_lo[32][8];
  const int tid  = threadIdx.x;
  const int wg   = blockIdx.x;
  const int j0   = wg * 8;
  const int lane = tid & 63;
  const int wv   = tid >> 6;       // wave 0..7

  // ---- stage Whh as hi/lo mfma A-fragments (once) ----
  for (int s = tid; s < 6144; s += 512) {
    const int ks = s >> 6, l = s & 63;
    const int r = l & 15;                 // A-row: 0-7 hi, 8-15 lo
    const int j = j0 + (r & 7);
    const int part = r >> 3;
    const int kb = ks*32 + (l >> 4)*8;
    const float* wp = Whh + (size_t)j*KH + kb;
    unsigned short tmp[8];
    #pragma unroll
    for (int i = 0; i < 8; ++i) {
      const float f = wp[i];
      unsigned short v = bf16_rne(f);
      if (part) v = bf16_rne(f - __uint_as_float((unsigned)v << 16));
      tmp[i] = v;
    }
    *(short8*)&w_lds[s*8] = *(short8*)tmp;
  }
  __syncthreads();

  const short8* wf  = (const short8*)w_lds;
  const short8* hi8 = (const short8*)hHi;
  const short8* lo8 = (const short8*)hLo;

  for (int t = 0; t < T_STEPS; ++t) {
    const size_t sb = (size_t)(128 - t) * 4096;   // slot base, 16B units
    f32x4 a0h = {}, a0l = {}, a1h = {}, a1l = {};

    // ---- phase A: dk1 + dk2 (operands ready since step t-2) ----
    #pragma unroll
    for (int i = 0; i < 8; ++i) {
      const int ks = 32 + (i >> 2)*32 + wv*4 + (i & 3);
      const short8 af = wf[ks*64 + lane];
      const size_t bidx = sb + (size_t)ks*128 + (size_t)(lane >> 4)*32 + (lane & 15);
      const short8 b0h = hi8[bidx];
      const short8 b1h = hi8[bidx + 16];
      const short8 b0l = lo8[bidx];
      const short8 b1l = lo8[bidx + 16];
      a0h = __builtin_amdgcn_mfma_f32_16x16x32_bf16(af, b0h, a0h, 0, 0, 0);
      a1h = __builtin_amdgcn_mfma_f32_16x16x32_bf16(af, b1h, a1h, 0, 0, 0);
      a0l = __builtin_amdgcn_mfma_f32_16x16x32_bf16(af, b0l, a0l, 0, 0, 0);
      a1l = __builtin_amdgcn_mfma_f32_16x16x32_bf16(af, b1l, a1l, 0, 0, 0);
    }

    // ---- wait for h_{t-1} complete (all 128 WGs flagged step t-1) ----
    if (t > 0) {
      while (__hip_atomic_load(&ready[t-1], __ATOMIC_RELAXED, __HIP_MEMORY_SCOPE_AGENT) != NWG)
        __builtin_amdgcn_s_sleep(4);
      asm volatile("" ::: "memory");   // no hoisting of slot loads above poll
    }

    // ---- phase C: dk0 (h_{t-1}) ----
    #pragma unroll
    for (int i = 0; i < 4; ++i) {
      const int ks = wv*4 + i;
      const short8 af = wf[ks*64 + lane];
      const size_t bidx = sb + (size_t)ks*128 + (size_t)(lane >> 4)*32 + (lane & 15);
      const short8 b0h = hi8[bidx];
      const short8 b1h = hi8[bidx + 16];
      const short8 b0l = lo8[bidx];
      const short8 b1l = lo8[bidx + 16];
      a0h = __builtin_amdgcn_mfma_f32_16x16x32_bf16(af, b0h, a0h, 0, 0, 0);
      a1h = __builtin_amdgcn_mfma_f32_16x16x32_bf16(af, b1h, a1h, 0, 0, 0);
      a0l = __builtin_amdgcn_mfma_f32_16x16x32_bf16(af, b0l, a0l, 0, 0, 0);
      a1l = __builtin_amdgcn_mfma_f32_16x16x32_bf16(af, b1l, a1l, 0, 0, 0);
    }

    const f32x4 s0 = a0h + a0l;
    const f32x4 s1 = a1h + a1l;
    const int rr = (lane >> 4) * 4, cc = lane & 15;
    #pragma unroll
    for (int q = 0; q < 4; ++q) {
      red[wv][rr + q][cc]      = s0[q];
      red[wv][rr + q][16 + cc] = s1[q];
    }
    __syncthreads();

    if (tid < 256) {
      const int jj = tid >> 5, b = tid & 31;
      float u = preT[(size_t)t*(H_DIM*BATCH) + (size_t)(j0 + jj)*BATCH + b];
      #pragma unroll
      for (int w = 0; w < 8; ++w)
        u += red[w][jj][b] + red[w][jj + 8][b];
      const float h = u > 0.f ? 1.0507009873554805f*u
                              : (1.0507009873554805f*1.6732632423543772f)*expm1f(u);
      const unsigned short hh = bf16_rne(h);
      hpk_hi[b][jj] = hh;
      hpk_lo[b][jj] = bf16_rne(h - __uint_as_float((unsigned)hh << 16));
    }
    __syncthreads();

    // ---- wave 0: coalesced sc1 h stores + A16 gather rows + flag ----
    if (tid < 32) {
      const int b = tid;
      const size_t base = (size_t)(127 - t)*SLOT_E + (size_t)(j0 >> 3)*256 + (size_t)b*8;
      const unsigned long long h0 = *(const unsigned long long*)&hpk_hi[b][0];
      const unsigned long long h1 = *(const unsigned long long*)&hpk_hi[b][4];
      const unsigned long long l0 = *(const unsigned long long*)&hpk_lo[b][0];
      const unsigned long long l1 = *(const unsigned long long*)&hpk_lo[b][4];
      __hip_atomic_store((unsigned long long*)(hHi + base),     h0, __ATOMIC_RELAXED, __HIP_MEMORY_SCOPE_AGENT);
      __hip_atomic_store((unsigned long long*)(hHi + base) + 1, h1, __ATOMIC_RELAXED, __HIP_MEMORY_SCOPE_AGENT);
      __hip_atomic_store((unsigned long long*)(hLo + base),     l0, __ATOMIC_RELAXED, __HIP_MEMORY_SCOPE_AGENT);
      __hip_atomic_store((unsigned long long*)(hLo + base) + 1, l1, __ATOMIC_RELAXED, __HIP_MEMORY_SCOPE_AGENT);
      const short8 vh = *(const short8*)&hpk_hi[b][0];
      #pragma unroll
      for (int dk = 0; dk < 4; ++dk) {
        const int tt = t + dk;
        if (tt < T_STEPS)
          *(short8*)(A16 + ((size_t)(tt*BATCH + b))*4096 + dk*H_DIM + j0) = vh;
      }
      asm volatile("s_waitcnt vmcnt(0)" ::: "memory");
      if (tid == 0)
        __hip_atomic_fetch_add(&ready[t], 1, __ATOMIC_RELAXED, __HIP_MEMORY_SCOPE_AGENT);
    }
    // no barrier: other waves proceed into next step's phase A
  }
}

// ---------------- out = A16 @ Wmo16^T  (bf16 MFMA, 128x128 tile) -----------
__global__ __launch_bounds__(256) void gemm_kernel(
    const unsigned short* __restrict__ A, const unsigned short* __restrict__ Bm,
    float* __restrict__ C) {
  __shared__ __align__(16) unsigned short lA[4096];  // [128 rows][32 k]
  __shared__ __align__(16) unsigned short lB[4096];
  const int tid = threadIdx.x;
  const int wg = blockIdx.x;
  // 2D-chunked XCD swizzle: XCD x owns mb [(x>>2)*16,+16), nb [(x&3)*16,+16)
  const int x = wg & 7;
  const int c = wg >> 3;
  const int mb = (x >> 2)*16 + (c & 15);
  const int nb = (x & 3)*16 + (c >> 4);
  const int lane = tid & 63;
  const int wv = tid >> 6;
  const int wm = wv >> 1, wn = wv & 1;
  const int lrow = lane & 15, lhalf = lane >> 4;
  const int rowA = tid >> 2, qA = tid & 3;
  f32x4 acc[4][4] = {};

  for (int kt = 0; kt < 128; ++kt) {
    __syncthreads();
    #pragma unroll
    for (int it = 0; it < 2; ++it) {
      const int row = it*64 + rowA;
      gload_lds16(A  + (size_t)(mb*128 + row)*4096 + kt*32 + qA*8,
                  &lA[(tid & 192)*8 + it*2048]);
      gload_lds16(Bm + (size_t)(nb*128 + row)*4096 + kt*32 + qA*8,
                  &lB[(tid & 192)*8 + it*2048]);
    }
    __syncthreads();   // barrier drains vmcnt -> LDS valid
    short8 af[4], bf[4];
    #pragma unroll
    for (int mi = 0; mi < 4; ++mi)
      af[mi] = *(const short8*)&lA[(wm*64 + mi*16 + lrow)*32 + lhalf*8];
    #pragma unroll
    for (int ni = 0; ni < 4; ++ni)
      bf[ni] = *(const short8*)&lB[(wn*64 + ni*16 + lrow)*32 + lhalf*8];
    #pragma unroll
    for (int mi = 0; mi < 4; ++mi)
      #pragma unroll
      for (int ni = 0; ni < 4; ++ni)
        acc[mi][ni] = __builtin_amdgcn_mfma_f32_16x16x32_bf16(af[mi], bf[ni], acc[mi][ni], 0, 0, 0);
  }
  const int orow0 = mb*128 + wm*64 + lhalf*4;
  const int ocol0 = nb*128 + wn*64 + lrow;
  #pragma unroll
  for (int mi = 0; mi < 4; ++mi)
    #pragma unroll
    for (int ni = 0; ni < 4; ++ni)
      #pragma unroll
      for (int q = 0; q < 4; ++q)
        __builtin_nontemporal_store(acc[mi][ni][q],
            &C[(size_t)(orow0 + mi*16 + q)*OUT_DIM + ocol0 + ni*16]);
}

extern "C" void kernel_launch(void* const* d_in, const int* in_sizes, int n_in,
                              void* d_out, int out_size, void* d_ws, size_t ws_size,
                              hipStream_t stream) {
  (void)in_sizes; (void)n_in; (void)out_size; (void)ws_size;
  const float* X   = (const float*)d_in[0];
  const float* Wxh = (const float*)d_in[1];
  const float* Wxb = (const float*)d_in[2];
  const float* Whh = (const float*)d_in[3];
  const float* Wmo = (const float*)d_in[4];
  float* out = (float*)d_out;
  char* ws = (char*)d_ws;

  const size_t OFF_PRET = 0;                                               // 16.8 MB
  const size_t OFF_HHI  = OFF_PRET + (size_t)T_STEPS*H_DIM*BATCH*4;
  const size_t OFF_HLO  = OFF_HHI + (size_t)NSLOT*SLOT_E*2;                // +8.6 MB
  const size_t OFF_RDY  = OFF_HLO + (size_t)NSLOT*SLOT_E*2;                // +8.6 MB
  const size_t OFF_A16  = OFF_RDY + 1024;
  const size_t OFF_W16  = OFF_A16 + (size_t)4096*4096*2;                   // +33.5 MB

  float* preT = (float*)(ws + OFF_PRET);
  unsigned short* hHi = (unsigned short*)(ws + OFF_HHI);
  unsigned short* hLo = (unsigned short*)(ws + OFF_HLO);
  int* ready = (int*)(ws + OFF_RDY);
  unsigned short* A16   = (unsigned short*)(ws + OFF_A16);
  unsigned short* Wmo16 = (unsigned short*)(ws + OFF_W16);

  // zero the three history slots (slots 128..130), ready flags, A16 t<3 cols
  hipMemsetAsync(hHi + (size_t)128*SLOT_E, 0, (size_t)3*SLOT_E*2, stream);
  hipMemsetAsync(hLo + (size_t)128*SLOT_E, 0, (size_t)3*SLOT_E*2, stream);
  hipMemsetAsync(ready, 0, 1024, stream);
  hipMemsetAsync(A16, 0, (size_t)96*4096*2, stream);

  convert_kernel<<<2048, 256, 0, stream>>>(Wmo, Wmo16, (int)((size_t)OUT_DIM*4096/4));
  pre_kernel<<<2048, 256, 0, stream>>>(X, Wxh, Wxb, preT);
  recur_kernel<<<NWG, 512, 0, stream>>>(Whh, preT, hHi, hLo, A16, ready);
  gemm_kernel<<<2048, 256, 0, stream>>>(A16, Wmo16, out);
}